// Round 13
// baseline (6029.147 us; speedup 1.0000x reference)
//
#include <hip/hip_runtime.h>

#define N 128
#define PAD2 129
#define NL 8128
#define POWER_IT 8    // even: last ortho is CholQR (orthonormal for Ritz)
#define INV_IT 3      // free: hidden under power window (32 chunks <= 60)
#define NTHREADS 1024

// Unified chunk schedule: waves 8..15 = power iteration, waves 0..7 = inverse chains.
// One __syncthreads per chunk; both sides decode their own state machine from c.
#define PCHUNKS (7 * POWER_IT + 4)   // 60
#define ICHUNKS (9 * INV_IT + 5)     // 32  (must be <= PCHUNKS)

// LDS layout (doubles first):
//   Ad[128*129] fp64 matrix (132096 B) -> L,U after LU
//   dinvd[128]  1/U[k,k]
//   dmisc[24]   [0]=lmax, [1..8]=lmin per inverse wave
//   dred[24]    power-side reduction scratch
//   dG[16]      4x4 R^{-1}, tid512 -> LDS broadcast
// then float4 region (padded index XI): fX4[143], fW4[143]
#define NDBL (16512 + 128 + 24 + 24 + 16)     // 16704 doubles = 133632 B
#define SMEM_BYTES (NDBL * 8 + 2 * 143 * 16)  // 138208
#define XI(j) ((j) + ((j) >> 3))              // bank-skew pad for float4 vectors

static __device__ __forceinline__ float hashf(unsigned x) {
    x ^= 2747636419u; x *= 2654435769u; x ^= x >> 16;
    x *= 2654435769u; x ^= x >> 16; x *= 2654435769u;
    return ((float)(x >> 8)) * (1.0f / 16777216.0f) - 0.5f;
}
static __device__ __forceinline__ double readlane_d(double x, int lane) {
    int lo = __builtin_amdgcn_readlane(__double2loint(x), lane);
    int hi = __builtin_amdgcn_readlane(__double2hiint(x), lane);
    return __hiloint2double(hi, lo);
}

// Cholesky of 4x4 Gram (packed upper, 10) -> C = R^{-1} (upper, row-major). tid512 only.
static __device__ __forceinline__ void cholInvC(const double* Gp, double* C) {
    double g[4][4];
    int c = 0;
    #pragma unroll
    for (int a = 0; a < 4; ++a)
        #pragma unroll
        for (int b2 = a; b2 < 4; ++b2) { g[a][b2] = Gp[c]; g[b2][a] = Gp[c]; ++c; }
    double R[4][4];
    #pragma unroll
    for (int i = 0; i < 4; ++i) {
        double d = g[i][i];
        #pragma unroll
        for (int m = 0; m < 4; ++m) if (m < i) d -= R[m][i] * R[m][i];
        d = sqrt(fmax(d, 1e-300));
        R[i][i] = d;
        #pragma unroll
        for (int j = 0; j < 4; ++j) if (j > i) {
            double v = g[i][j];
            #pragma unroll
            for (int m = 0; m < 4; ++m) if (m < i) v -= R[m][i] * R[m][j];
            R[i][j] = v / d;
        }
    }
    #pragma unroll
    for (int j = 3; j >= 0; --j) {
        C[j*4 + j] = 1.0 / R[j][j];
        #pragma unroll
        for (int i = 3; i >= 0; --i) if (i < j) {
            double v = 0.0;
            #pragma unroll
            for (int m = 0; m < 4; ++m) if (m > i && m <= j) v += R[i][m] * C[m*4 + j];
            C[i*4 + j] = -v / R[i][i];
        }
        #pragma unroll
        for (int i = 0; i < 4; ++i) if (i > j) C[i*4 + j] = 0.0;
    }
}

static __device__ __forceinline__ double jacobi4_lmax(const double* Gp) {
    double g[4][4];
    int c = 0;
    #pragma unroll
    for (int a = 0; a < 4; ++a)
        #pragma unroll
        for (int b2 = a; b2 < 4; ++b2) { g[a][b2] = Gp[c]; g[b2][a] = Gp[c]; ++c; }
    #pragma unroll
    for (int sweep = 0; sweep < 6; ++sweep) {
        #pragma unroll
        for (int p = 0; p < 3; ++p) {
            #pragma unroll
            for (int q = p + 1; q < 4; ++q) {
                double apq = g[p][q];
                double tau = (g[q][q] - g[p][p]) / (2.0 * apq);
                double t = (tau >= 0.0 ? 1.0 : -1.0) / (fabs(tau) + sqrt(1.0 + tau * tau));
                if (fabs(apq) < 1e-280) t = 0.0;
                double cc = 1.0 / sqrt(1.0 + t * t);
                double ss = t * cc;
                #pragma unroll
                for (int r = 0; r < 4; ++r) {
                    double grp = g[r][p], grq = g[r][q];
                    g[r][p] = cc * grp - ss * grq;
                    g[r][q] = ss * grp + cc * grq;
                }
                #pragma unroll
                for (int r = 0; r < 4; ++r) {
                    double gpr = g[p][r], gqr = g[q][r];
                    g[p][r] = cc * gpr - ss * gqr;
                    g[q][r] = ss * gpr + cc * gqr;
                }
            }
        }
    }
    return fmax(fmax(g[0][0], g[1][1]), fmax(g[2][2], g[3][3]));
}

static __device__ __forceinline__ void cholqr2_d(double ya[2], double yb[2]) {
    double g00 = ya[0]*ya[0] + yb[0]*yb[0];
    double g01 = ya[0]*ya[1] + yb[0]*yb[1];
    double g11 = ya[1]*ya[1] + yb[1]*yb[1];
    #pragma unroll
    for (int o = 32; o > 0; o >>= 1) {
        g00 += __shfl_xor(g00, o);
        g01 += __shfl_xor(g01, o);
        g11 += __shfl_xor(g11, o);
    }
    double r00 = sqrt(fmax(g00, 1e-300));
    double r01 = g01 / r00;
    double r11 = sqrt(fmax(g11 - r01 * r01, fabs(g11) * 1e-26 + 1e-300));
    double c00 = 1.0 / r00, c11 = 1.0 / r11;
    double c01 = -r01 * c00 * c11;
    double a0 = ya[0]*c00,             b0 = yb[0]*c00;
    double a1 = ya[0]*c01 + ya[1]*c11, b1 = yb[0]*c01 + yb[1]*c11;
    ya[0] = a0; yb[0] = b0; ya[1] = a1; yb[1] = b1;
}

// Power sweep on 512 threads (waves 8..15): row pr = tid2>>2, lane pc = tid2&3
// handles contiguous cols [pc*32, pc*32+32). Direct LDS reads (rule #20).
// MODE 0: out=U*in (j>=pr) | 1: out=L*in unit (j<pr,+in) | 2: out=L^T*in unit (j>pr,+in) | 3: out=U^T*in (j<=pr)
template<int MODE>
static __device__ __forceinline__ void sweepP(const double* __restrict__ Ad,
                                              const float4* __restrict__ Xin,
                                              float4* __restrict__ Xout,
                                              int pr, int pc) {
    const int jbase = pc << 5;
    float a0 = 0.f, a1 = 0.f, a2 = 0.f, a3 = 0.f;
    #pragma unroll
    for (int t = 0; t < 32; ++t) {
        int j = jbase + t;
        float a = (MODE < 2) ? (float)Ad[pr * PAD2 + j] : (float)Ad[j * PAD2 + pr];
        bool keep = (MODE == 0) ? (j >= pr) : (MODE == 1) ? (j < pr)
                  : (MODE == 2) ? (j > pr)  : (j <= pr);
        a = keep ? a : 0.f;
        float4 xv = Xin[XI(j)];
        a0 += a * xv.x; a1 += a * xv.y; a2 += a * xv.z; a3 += a * xv.w;
    }
    a0 += __shfl_xor(a0, 1); a0 += __shfl_xor(a0, 2);
    a1 += __shfl_xor(a1, 1); a1 += __shfl_xor(a1, 2);
    a2 += __shfl_xor(a2, 1); a2 += __shfl_xor(a2, 2);
    a3 += __shfl_xor(a3, 1); a3 += __shfl_xor(a3, 2);
    if (pc == 0) {
        float4 o = make_float4(a0, a1, a2, a3);
        if (MODE == 1 || MODE == 2) {
            float4 iv = Xin[XI(pr)];
            o.x += iv.x; o.y += iv.y; o.z += iv.z; o.w += iv.w;
        }
        Xout[XI(pr)] = o;
    }
}

__global__ __launch_bounds__(NTHREADS)
__attribute__((amdgpu_waves_per_eu(4, 4)))
void cond_kernel(const float* __restrict__ DD, const float* __restrict__ LE,
                 const float* __restrict__ SCL, double* __restrict__ conds)
{
    extern __shared__ char smraw[];
    double* Ad    = (double*)smraw;        // 16512
    double* dinvd = Ad + N * PAD2;         // 128
    double* dmisc = dinvd + 128;           // 24
    double* dred  = dmisc + 24;            // 24
    double* dG    = dred + 24;             // 16
    float4* fX4   = (float4*)(Ad + NDBL);  // 143
    float4* fW4   = fX4 + 143;             // 143

    const int tid = threadIdx.x;
    const int b   = blockIdx.x;
    const int wid = tid >> 6;
    const int l   = tid & 63;
    const int rB  = l + 64;
    const double s = (double)SCL[0];
    const float* dd = DD + (size_t)b * (N * N);
    const float* le = LE + (size_t)b * NL;

    // ---- stage DD -> fp64
    for (int t = tid; t < (N * N) / 4; t += NTHREADS) {
        float4 dv = reinterpret_cast<const float4*>(dd)[t];
        int elem = t * 4;
        int i = elem >> 7, j = elem & 127;
        double* dst = &Ad[i * PAD2 + j];
        dst[0] = (double)dv.x; dst[1] = (double)dv.y;
        dst[2] = (double)dv.z; dst[3] = (double)dv.w;
    }
    __syncthreads();

    const int pr_ = tid >> 5;   // 0..31: row in 32-row block
    const int pc_ = tid & 31;   // col group: cols pc_+32e, e<4

    // ---- Pass A: T = D + s * E^T D (E = strict-lower le), ascending 32-row blocks
    for (int KB = 0; KB < N; KB += 32) {
        const int k = KB + pr_;
        double acc[4];
        #pragma unroll
        for (int e = 0; e < 4; ++e) acc[e] = 0.0;
        int off = (KB + 1) * KB / 2 + k;
        #pragma unroll 4
        for (int i = KB + 1; i < N; ++i) {
            int offs = (i > k) ? off : 0;
            float lef = le[offs];
            double lv = (i > k) ? (double)lef : 0.0;
            #pragma unroll
            for (int e = 0; e < 4; ++e) acc[e] += lv * Ad[i * PAD2 + pc_ + 32 * e];
            off += i;
        }
        __syncthreads();
        #pragma unroll
        for (int e = 0; e < 4; ++e) Ad[k * PAD2 + pc_ + 32 * e] += s * acc[e];
        __syncthreads();
    }

    // ---- Pass B: P = T + s * E T, descending 32-row blocks
    for (int IB = N - 32; IB >= 0; IB -= 32) {
        const int i = IB + pr_;
        const float* er = le + i * (i - 1) / 2;
        double acc[4];
        #pragma unroll
        for (int e = 0; e < 4; ++e) acc[e] = 0.0;
        #pragma unroll 4
        for (int m = 0; m < IB + 32; ++m) {
            int mm = (m < i) ? m : 0;
            float lef = er[mm];
            double lv = (m < i) ? (double)lef : 0.0;
            #pragma unroll
            for (int e = 0; e < 4; ++e) acc[e] += lv * Ad[m * PAD2 + pc_ + 32 * e];
        }
        __syncthreads();
        #pragma unroll
        for (int e = 0; e < 4; ++e) Ad[i * PAD2 + pc_ + 32 * e] += s * acc[e];
        __syncthreads();
    }

    // ---- LU with partial pivoting, in place, fp64
    for (int k = 0; k < N - 1; ++k) {
        if (wid == 0) {
            float v0 = (l >= k) ? (float)fabs(Ad[l * PAD2 + k]) : -1.0f;
            float v1 = (rB >= k) ? (float)fabs(Ad[rB * PAD2 + k]) : -1.0f;
            float vm = v0; int im = l;
            if (v1 > vm) { vm = v1; im = rB; }
            #pragma unroll
            for (int o = 32; o > 0; o >>= 1) {
                float ov = __shfl_xor(vm, o);
                int   oi = __shfl_xor(im, o);
                if (ov > vm) { vm = ov; im = oi; }
            }
            if (l == 0) dinvd[k] = 1.0 / Ad[im * PAD2 + k];
            if (im != k) {
                double t0 = Ad[k * PAD2 + l];
                Ad[k * PAD2 + l] = Ad[im * PAD2 + l];
                Ad[im * PAD2 + l] = t0;
                double t1 = Ad[k * PAD2 + rB];
                Ad[k * PAD2 + rB] = Ad[im * PAD2 + rB];
                Ad[im * PAD2 + rB] = t1;
            }
        }
        __syncthreads();
        double invd = dinvd[k];
        int g32 = tid >> 5, l32 = tid & 31;
        double ukj[4];
        #pragma unroll
        for (int m2 = 0; m2 < 4; ++m2) {
            int j = k + 1 + l32 + 32 * m2;
            ukj[m2] = (j < N) ? Ad[k * PAD2 + j] : 0.0;
        }
        #pragma unroll 2
        for (int i = k + 1 + g32; i < N; i += 32) {
            double lik = Ad[i * PAD2 + k] * invd;
            if (l32 == 0) Ad[i * PAD2 + k] = lik;
            #pragma unroll
            for (int m2 = 0; m2 < 4; ++m2) {
                int j = k + 1 + l32 + 32 * m2;
                if (j < N) Ad[i * PAD2 + j] -= lik * ukj[m2];
            }
        }
        __syncthreads();
    }
    if (tid == 0) dinvd[N - 1] = 1.0 / Ad[(N - 1) * PAD2 + (N - 1)];

    // ---- init both phases
    const int tid2 = tid - 512;          // power-side index (waves 8..15)
    const int prP  = tid2 >> 2;          // power row (valid when tid2 >= 0)
    const int pcP  = tid2 & 3;
    const int wv2  = tid2 >> 6;          // 0/1 for tid2 < 128

    if (wid >= 8 && tid2 < 128) {
        float4 xv;
        xv.x = hashf(13u + (unsigned)tid2 * 7919u);
        xv.y = hashf(14u + (unsigned)tid2 * 7919u);
        xv.z = hashf(15u + (unsigned)tid2 * 7919u);
        xv.w = hashf(16u + (unsigned)tid2 * 7919u);
        fX4[XI(tid2)] = xv;
    }
    // inverse-side persistent state (registers live across chunks)
    double ya[2] = {0, 0}, yb[2] = {0, 0};
    double rt0[2] = {0, 0}, rt1[2] = {0, 0}, rz0[2] = {0, 0}, rz1[2] = {0, 0};
    if (wid < 8) {
        unsigned seed = 2654435761u * (unsigned)(wid + 1) + 12345u;
        #pragma unroll
        for (int v = 0; v < 2; ++v) {
            ya[v] = (double)hashf(seed + (unsigned)(v * 337 + l * 101 + 7));
            yb[v] = (double)hashf(seed + (unsigned)(v * 337 + rB * 101 + 7));
        }
    }
    __syncthreads();

    // ================= unified overlap loop: power (waves 8..15) || inverse (waves 0..7) ====
    for (int c = 0; c < PCHUNKS; ++c) {
        if (wid >= 8) {
            // ---------------- power side ----------------
            if (c < 7 * POWER_IT) {
                const int itp = c / 7, ph = c % 7;
                if      (ph == 0) sweepP<0>(Ad, fX4, fW4, prP, pcP);
                else if (ph == 1) sweepP<1>(Ad, fW4, fX4, prP, pcP);
                else if (ph == 2) sweepP<2>(Ad, fX4, fW4, prP, pcP);
                else if (ph == 3) sweepP<3>(Ad, fW4, fX4, prP, pcP);
                else if (ph == 4) {
                    if (tid2 < 128) {
                        float4 x = fX4[XI(tid2)];
                        if ((itp & 1) == 0) {
                            float n0 = x.x*x.x, n1 = x.y*x.y, n2 = x.z*x.z, n3 = x.w*x.w;
                            #pragma unroll
                            for (int o = 32; o > 0; o >>= 1) {
                                n0 += __shfl_xor(n0, o); n1 += __shfl_xor(n1, o);
                                n2 += __shfl_xor(n2, o); n3 += __shfl_xor(n3, o);
                            }
                            if (l == 0) {
                                dred[wv2*4 + 0] = (double)n0; dred[wv2*4 + 1] = (double)n1;
                                dred[wv2*4 + 2] = (double)n2; dred[wv2*4 + 3] = (double)n3;
                            }
                        } else {
                            float xs[4] = {x.x, x.y, x.z, x.w};
                            double p[10];
                            { int cc = 0;
                              #pragma unroll
                              for (int v = 0; v < 4; ++v)
                                  #pragma unroll
                                  for (int w2 = v; w2 < 4; ++w2) { p[cc] = (double)xs[v] * xs[w2]; ++cc; } }
                            #pragma unroll
                            for (int o = 32; o > 0; o >>= 1)
                                #pragma unroll
                                for (int c2 = 0; c2 < 10; ++c2) p[c2] += __shfl_xor(p[c2], o);
                            if (l == 0)
                                for (int c2 = 0; c2 < 10; ++c2) dred[wv2*10 + c2] = p[c2];
                        }
                    }
                } else if (ph == 5) {
                    if ((itp & 1) == 1 && tid == 512) {
                        double Gp[10];
                        #pragma unroll
                        for (int c2 = 0; c2 < 10; ++c2) Gp[c2] = dred[c2] + dred[10 + c2];
                        cholInvC(Gp, dG);
                    }
                } else { // ph == 6: apply normalization / CholQR factor
                    if (tid2 < 128) {
                        float4 x = fX4[XI(tid2)];
                        if ((itp & 1) == 0) {
                            float i0 = rsqrtf((float)(dred[0] + dred[4]) + 1e-30f);
                            float i1 = rsqrtf((float)(dred[1] + dred[5]) + 1e-30f);
                            float i2 = rsqrtf((float)(dred[2] + dred[6]) + 1e-30f);
                            float i3 = rsqrtf((float)(dred[3] + dred[7]) + 1e-30f);
                            x.x *= i0; x.y *= i1; x.z *= i2; x.w *= i3;
                            fX4[XI(tid2)] = x;
                        } else {
                            double x0 = x.x, x1 = x.y, x2 = x.z, x3 = x.w;
                            float n0 = (float)(dG[0]*x0);
                            float n1 = (float)(dG[1]*x0 + dG[5]*x1);
                            float n2 = (float)(dG[2]*x0 + dG[6]*x1 + dG[10]*x2);
                            float n3 = (float)(dG[3]*x0 + dG[7]*x1 + dG[11]*x2 + dG[15]*x3);
                            fX4[XI(tid2)] = make_float4(n0, n1, n2, n3);
                        }
                    }
                }
            } else {
                const int rc = c - 7 * POWER_IT;   // Ritz for lambda_max
                if      (rc == 0) sweepP<0>(Ad, fX4, fW4, prP, pcP);
                else if (rc == 1) sweepP<1>(Ad, fW4, fX4, prP, pcP);
                else if (rc == 2) {
                    if (tid2 < 128) {
                        float4 x = fX4[XI(tid2)];
                        float xs[4] = {x.x, x.y, x.z, x.w};
                        double p[10];
                        { int cc = 0;
                          #pragma unroll
                          for (int v = 0; v < 4; ++v)
                              #pragma unroll
                              for (int w2 = v; w2 < 4; ++w2) { p[cc] = (double)xs[v] * xs[w2]; ++cc; } }
                        #pragma unroll
                        for (int o = 32; o > 0; o >>= 1)
                            #pragma unroll
                            for (int c2 = 0; c2 < 10; ++c2) p[c2] += __shfl_xor(p[c2], o);
                        if (l == 0)
                            for (int c2 = 0; c2 < 10; ++c2) dred[wv2*10 + c2] = p[c2];
                    }
                } else { // rc == 3
                    if (tid == 512) {
                        double Gp[10];
                        #pragma unroll
                        for (int c2 = 0; c2 < 10; ++c2) Gp[c2] = dred[c2] + dred[10 + c2];
                        dmisc[0] = jacobi4_lmax(Gp);
                    }
                }
            }
        } else {
            // ---------------- inverse side (state machine over serial chains) ----------------
            if (c < 9 * INV_IT) {
                const int ph = c % 9;
                if (ph == 0) {                      // (a) U^T a = y, rows 0..63
                    #pragma unroll 4
                    for (int i = 0; i < 64; ++i) {
                        double invd = dinvd[i];
                        double u0 = Ad[i * PAD2 + l];
                        double u1 = Ad[i * PAD2 + rB];
                        bool up0 = (l > i);
                        #pragma unroll
                        for (int v = 0; v < 2; ++v) {
                            double av = readlane_d(ya[v], i) * invd;
                            double upd = ya[v] - u0 * av;
                            ya[v] = (l == i) ? av : (up0 ? upd : ya[v]);
                            yb[v] -= u1 * av;
                        }
                    }
                } else if (ph == 1) {               // (a) rows 64..127
                    #pragma unroll 4
                    for (int i2 = 0; i2 < 64; ++i2) {
                        double invd = dinvd[64 + i2];
                        double u1 = Ad[(64 + i2) * PAD2 + rB];
                        bool up1 = (l > i2);
                        #pragma unroll
                        for (int v = 0; v < 2; ++v) {
                            double av = readlane_d(yb[v], i2) * invd;
                            double upd = yb[v] - u1 * av;
                            yb[v] = (l == i2) ? av : (up1 ? upd : yb[v]);
                        }
                    }
                } else if (ph == 2) {               // (b) L^T b = a, rows 127..64
                    #pragma unroll 4
                    for (int j2 = 63; j2 >= 0; --j2) {
                        int j = 64 + j2;
                        double L0 = Ad[j * PAD2 + l];
                        double L1 = Ad[j * PAD2 + rB];
                        bool m1 = (l < j2);
                        #pragma unroll
                        for (int v = 0; v < 2; ++v) {
                            double bv = readlane_d(yb[v], j2);
                            ya[v] -= L0 * bv;
                            double upd = yb[v] - L1 * bv;
                            yb[v] = m1 ? upd : yb[v];
                        }
                    }
                } else if (ph == 3) {               // (b) rows 63..1
                    #pragma unroll 4
                    for (int j = 63; j >= 1; --j) {
                        double L0 = Ad[j * PAD2 + l];
                        bool m0 = (l < j);
                        #pragma unroll
                        for (int v = 0; v < 2; ++v) {
                            double bv = readlane_d(ya[v], j);
                            double upd = ya[v] - L0 * bv;
                            ya[v] = m0 ? upd : ya[v];
                        }
                    }
                } else if (ph == 4) {               // (c) L c = b, rows 0..63
                    #pragma unroll 4
                    for (int j = 0; j < 64; ++j) {
                        double La0 = Ad[l * PAD2 + j];
                        double La1 = Ad[rB * PAD2 + j];
                        bool m0 = (l > j);
                        #pragma unroll
                        for (int v = 0; v < 2; ++v) {
                            double cv = readlane_d(ya[v], j);
                            double upd = ya[v] - La0 * cv;
                            ya[v] = m0 ? upd : ya[v];
                            yb[v] -= La1 * cv;
                        }
                    }
                } else if (ph == 5) {               // (c) rows 64..127
                    #pragma unroll 4
                    for (int j2 = 0; j2 < 64; ++j2) {
                        double La1 = Ad[rB * PAD2 + 64 + j2];
                        bool m1 = (l > j2);
                        #pragma unroll
                        for (int v = 0; v < 2; ++v) {
                            double cv = readlane_d(yb[v], j2);
                            double upd = yb[v] - La1 * cv;
                            yb[v] = m1 ? upd : yb[v];
                        }
                    }
                } else if (ph == 6) {               // (d) U x = c, rows 127..64
                    #pragma unroll 4
                    for (int i2 = 63; i2 >= 0; --i2) {
                        int i = 64 + i2;
                        double invd = dinvd[i];
                        double U0 = Ad[l * PAD2 + i];
                        double U1 = Ad[rB * PAD2 + i];
                        bool m1 = (l < i2);
                        #pragma unroll
                        for (int v = 0; v < 2; ++v) {
                            double xv = readlane_d(yb[v], i2) * invd;
                            ya[v] -= U0 * xv;
                            double upd = yb[v] - U1 * xv;
                            yb[v] = (l == i2) ? xv : (m1 ? upd : yb[v]);
                        }
                    }
                } else if (ph == 7) {               // (d) rows 63..0
                    #pragma unroll 4
                    for (int i = 63; i >= 0; --i) {
                        double invd = dinvd[i];
                        double U0 = Ad[l * PAD2 + i];
                        bool m0 = (l < i);
                        #pragma unroll
                        for (int v = 0; v < 2; ++v) {
                            double xv = readlane_d(ya[v], i) * invd;
                            double upd = ya[v] - U0 * xv;
                            ya[v] = (l == i) ? xv : (m0 ? upd : ya[v]);
                        }
                    }
                } else {                            // ph == 8: orthonormalize
                    cholqr2_d(ya, yb);
                }
            } else if (c < ICHUNKS) {
                const int rc = c - 9 * INV_IT;      // Ritz for lambda_min: z = L U y
                if (rc == 0) {
                    #pragma unroll 4
                    for (int j = 0; j < 64; ++j) {
                        double u0 = Ad[l * PAD2 + j];
                        u0 = (j >= l) ? u0 : 0.0;
                        #pragma unroll
                        for (int v = 0; v < 2; ++v) { double yj = readlane_d(ya[v], j); rt0[v] += u0 * yj; }
                    }
                } else if (rc == 1) {
                    #pragma unroll 4
                    for (int j2 = 0; j2 < 64; ++j2) {
                        int j = 64 + j2;
                        double u0 = Ad[l * PAD2 + j];
                        double u1 = Ad[rB * PAD2 + j];
                        u1 = (j2 >= l) ? u1 : 0.0;
                        #pragma unroll
                        for (int v = 0; v < 2; ++v) {
                            double yj = readlane_d(yb[v], j2);
                            rt0[v] += u0 * yj; rt1[v] += u1 * yj;
                        }
                    }
                } else if (rc == 2) {
                    #pragma unroll
                    for (int v = 0; v < 2; ++v) { rz0[v] = rt0[v]; rz1[v] = rt1[v]; }
                    #pragma unroll 4
                    for (int j = 0; j < 64; ++j) {
                        double L0 = Ad[l * PAD2 + j];
                        L0 = (j < l) ? L0 : 0.0;
                        double L1 = Ad[rB * PAD2 + j];
                        #pragma unroll
                        for (int v = 0; v < 2; ++v) {
                            double tj = readlane_d(rt0[v], j);
                            rz0[v] += L0 * tj; rz1[v] += L1 * tj;
                        }
                    }
                } else if (rc == 3) {
                    #pragma unroll 4
                    for (int j2 = 0; j2 < 64; ++j2) {
                        double L1 = Ad[rB * PAD2 + 64 + j2];
                        L1 = (j2 < l) ? L1 : 0.0;
                        #pragma unroll
                        for (int v = 0; v < 2; ++v) {
                            double tj = readlane_d(rt1[v], j2);
                            rz1[v] += L1 * tj;
                        }
                    }
                } else { // rc == 4: 2x2 Gram -> lmin
                    double g00 = rz0[0]*rz0[0] + rz1[0]*rz1[0];
                    double g01 = rz0[0]*rz0[1] + rz1[0]*rz1[1];
                    double g11 = rz0[1]*rz0[1] + rz1[1]*rz1[1];
                    #pragma unroll
                    for (int o = 32; o > 0; o >>= 1) {
                        g00 += __shfl_xor(g00, o);
                        g01 += __shfl_xor(g01, o);
                        g11 += __shfl_xor(g11, o);
                    }
                    double dif = g00 - g11;
                    double lmin = 0.5 * ((g00 + g11) - sqrt(dif * dif + 4.0 * g01 * g01));
                    if (l == 0) dmisc[1 + wid] = lmin;
                }
            }
            // chunks [ICHUNKS, PCHUNKS): idle, just hit the barrier
        }
        __syncthreads();
    }

    if (tid == 0) {
        double lmin = dmisc[1];
        #pragma unroll
        for (int w2 = 2; w2 <= 8; ++w2) lmin = fmin(lmin, dmisc[w2]);
        conds[b] = sqrt(fmax(dmisc[0], 0.0) / fmax(lmin, 1e-290));
    }
}

__global__ void reduce_kernel(const double* __restrict__ conds, float* __restrict__ out, int B) {
    __shared__ double sred[4];
    int tid = threadIdx.x;
    double acc = 0.0;
    for (int i = tid; i < B; i += 256) acc += conds[i];
    #pragma unroll
    for (int o = 32; o > 0; o >>= 1) acc += __shfl_xor(acc, o);
    if ((tid & 63) == 0) sred[tid >> 6] = acc;
    __syncthreads();
    if (tid == 0) out[0] = (float)((sred[0] + sred[1] + sred[2] + sred[3]) / (double)B);
}

extern "C" void kernel_launch(void* const* d_in, const int* in_sizes, int n_in,
                              void* d_out, int out_size, void* d_ws, size_t ws_size,
                              hipStream_t stream) {
    const float* DD = (const float*)d_in[0];
    const float* LE = (const float*)d_in[1];
    const float* SC = (const float*)d_in[2];
    float* out = (float*)d_out;
    int B = in_sizes[0] / (N * N);
    double* conds = (double*)d_ws;

    static_assert(ICHUNKS <= PCHUNKS, "inverse must fit under power window");
    static_assert(SMEM_BYTES <= 160 * 1024, "LDS budget");
    (void)hipFuncSetAttribute((const void*)cond_kernel,
                              hipFuncAttributeMaxDynamicSharedMemorySize, (int)SMEM_BYTES);
    hipLaunchKernelGGL(cond_kernel, dim3(B), dim3(NTHREADS), SMEM_BYTES, stream, DD, LE, SC, conds);
    hipLaunchKernelGGL(reduce_kernel, dim3(1), dim3(256), 0, stream, conds, out, B);
}